// Round 5
// baseline (105.286 us; speedup 1.0000x reference)
//
#include <hip/hip_runtime.h>

#define HCH 32
#define NDIM 1024
#define SEG 512                // pixels per wave (half row)
#define ITERS (SEG / 32)       // 16 iterations of 32 px (2 groups of 16)

using half2v  = __attribute__((ext_vector_type(2))) _Float16;
using half8   = __attribute__((ext_vector_type(8))) _Float16;
using floatx4 = __attribute__((ext_vector_type(4))) float;

// One wave per half-row. 16x16x32 MFMA shape (register-lean):
//   lane: px = lane&15, quad = lane>>4.
//   layer1: lane computes h1 channels quad*8+{0..7} for its px (packed f16)
//           -> B-frag B[k=quad*8+j][n=px] directly, no redundancy.
//   layer2: D_lo = W2[:, 0:16]^T.h1 + b2_lo, D_hi likewise (share B-frag).
//           C/D: col=lane&15=px, row(out-ch) = quad*4+reg (+16 for hi).
//   layer3: 8 relu+fma per lane, butterfly shfl_xor(16),(32) over quads.
//   Two independent 16-px groups per iteration for ILP; one masked 128B store.
__global__ __launch_bounds__(256, 4)
void lf_kernel(const float* __restrict__ weights,
               const float* __restrict__ distances,
               const float* __restrict__ W1,
               const float* __restrict__ b1,
               const float* __restrict__ W2,
               const float* __restrict__ b2,
               const float* __restrict__ W3,
               const float* __restrict__ b3,
               float* __restrict__ out)
{
    const int lane = threadIdx.x & 63;
    // Force wave-uniform values into SGPRs: row bases become scalar,
    // loads become [SGPR base + small voffset + imm].
    const int wave_gid = __builtin_amdgcn_readfirstlane(blockIdx.x * 4 + (threadIdx.x >> 6));
    const int row_id = wave_gid >> 1;          // (b,i) row
    const int j_begin = (wave_gid & 1) * SEG;  // half within the row
    const int b = row_id >> 10;                // N = 1024

    const int px = lane & 15;
    const int quad = lane >> 4;                // 0..3
    const int kb = quad * 8;                   // this lane's h1/B-frag channels

    const float wi = weights[row_id];

    // Layer-1 constants for channels kb+{0..7} as 4 f16 pairs.
    // base = W1[0,ch]*wi + b1[ch] folded in f32 once per wave.
    half2v base2[4], cc2[4], ee2[4];
#pragma unroll
    for (int p = 0; p < 4; ++p) {
        const int chA = kb + 2 * p;
        const int chB = chA + 1;
        base2[p] = half2v{(_Float16)fmaf(W1[chA], wi, b1[chA]),
                          (_Float16)fmaf(W1[chB], wi, b1[chB])};
        cc2[p] = half2v{(_Float16)W1[HCH + chA], (_Float16)W1[HCH + chB]};
        ee2[p] = half2v{(_Float16)W1[2 * HCH + chA], (_Float16)W1[2 * HCH + chB]};
    }

    // A-frags: A[m][k] with m=px(lane&15), k=kb+j.  lo: out-ch 0..15, hi: 16..31.
    half8 a_lo, a_hi;
#pragma unroll
    for (int j = 0; j < 8; ++j) {
        a_lo[j] = (_Float16)W2[(kb + j) * HCH + px];
        a_hi[j] = (_Float16)W2[(kb + j) * HCH + 16 + px];
    }

    // C-init (b2) and W3, indexed by this lane's out-channels quad*4+r (+16).
    floatx4 ci_lo, ci_hi;
    float w3lo[4], w3hi[4];
#pragma unroll
    for (int r = 0; r < 4; ++r) {
        ci_lo[r] = b2[quad * 4 + r];
        ci_hi[r] = b2[16 + quad * 4 + r];
        w3lo[r]  = W3[quad * 4 + r];
        w3hi[r]  = W3[16 + quad * 4 + r];
    }
    const float b3v = b3[0];

    const float* __restrict__ drow = distances + (size_t)row_id * NDIM + j_begin;
    const float* __restrict__ wrow = weights + b * NDIM + j_begin;
    float* __restrict__ orow = out + (size_t)row_id * NDIM + j_begin;

    // Depth-2 prefetch ring for the streaming d / wj values (2 groups each).
    float dbuf[2][2], wbuf[2][2];
#pragma unroll
    for (int t = 0; t < 2; ++t) {
        dbuf[t][0] = drow[t * 32 + px];
        dbuf[t][1] = drow[t * 32 + 16 + px];
        wbuf[t][0] = wrow[t * 32 + px];
        wbuf[t][1] = wrow[t * 32 + 16 + px];
    }

    const half2v zero2 = half2v{(_Float16)0.0f, (_Float16)0.0f};

#pragma unroll
    for (int t = 0; t < ITERS; ++t) {
        const int cur = t & 1;
        const float dA = dbuf[cur][0], dB = dbuf[cur][1];
        const float wA = wbuf[cur][0], wB = wbuf[cur][1];

        // Prefetch t+2 into the slot just freed (register-renamed by compiler).
        const int tp = (t + 2 < ITERS) ? (t + 2) : (t + 2 - ITERS);
        dbuf[cur][0] = drow[tp * 32 + px];
        dbuf[cur][1] = drow[tp * 32 + 16 + px];
        wbuf[cur][0] = wrow[tp * 32 + px];
        wbuf[cur][1] = wrow[tp * 32 + 16 + px];

        // ---- Layer 1 (packed f16), two independent 16-px groups ----
        const _Float16 dhA = (_Float16)dA, whA = (_Float16)wA;
        const _Float16 dhB = (_Float16)dB, whB = (_Float16)wB;
        const half2v d2A = half2v{dhA, dhA}, w2A = half2v{whA, whA};
        const half2v d2B = half2v{dhB, dhB}, w2B = half2v{whB, whB};

        union Frag { half8 v; half2v h[4]; } fA, fB;
#pragma unroll
        for (int p = 0; p < 4; ++p) {
            half2v tA = __builtin_elementwise_fma(cc2[p], w2A, base2[p]);
            tA = __builtin_elementwise_fma(ee2[p], d2A, tA);
            fA.h[p] = __builtin_elementwise_max(tA, zero2);
            half2v tB = __builtin_elementwise_fma(cc2[p], w2B, base2[p]);
            tB = __builtin_elementwise_fma(ee2[p], d2B, tB);
            fB.h[p] = __builtin_elementwise_max(tB, zero2);
        }

        // ---- Layer 2: 4 independent MFMAs (lo/hi share each group's B) ----
        floatx4 aAlo = __builtin_amdgcn_mfma_f32_16x16x32_f16(a_lo, fA.v, ci_lo, 0, 0, 0);
        floatx4 aAhi = __builtin_amdgcn_mfma_f32_16x16x32_f16(a_hi, fA.v, ci_hi, 0, 0, 0);
        floatx4 aBlo = __builtin_amdgcn_mfma_f32_16x16x32_f16(a_lo, fB.v, ci_lo, 0, 0, 0);
        floatx4 aBhi = __builtin_amdgcn_mfma_f32_16x16x32_f16(a_hi, fB.v, ci_hi, 0, 0, 0);

        // ---- Layer 3: relu + W3 dot over this lane's 8 out-channels ----
        float sA = 0.0f, sB = 0.0f;
#pragma unroll
        for (int r = 0; r < 4; ++r) {
            sA = fmaf(fmaxf(aAlo[r], 0.0f), w3lo[r], sA);
            sA = fmaf(fmaxf(aAhi[r], 0.0f), w3hi[r], sA);
            sB = fmaf(fmaxf(aBlo[r], 0.0f), w3lo[r], sB);
            sB = fmaf(fmaxf(aBhi[r], 0.0f), w3hi[r], sB);
        }
        // Butterfly over the 4 quads (both groups, 2 shuffles each).
        sA += __shfl_xor(sA, 16, 64);
        sA += __shfl_xor(sA, 32, 64);
        sB += __shfl_xor(sB, 16, 64);
        sB += __shfl_xor(sB, 32, 64);

        // lanes 0-15 -> group A px, lanes 16-31 -> group B px
        const float s_sel = (lane & 16) ? sB : sA;
        const float x = s_sel + b3v;
        const float sp = fmaxf(x, 0.0f) + __logf(1.0f + __expf(-fabsf(x)));

        if (lane < 32) orow[t * 32 + lane] = sp;
    }
}

extern "C" void kernel_launch(void* const* d_in, const int* in_sizes, int n_in,
                              void* d_out, int out_size, void* d_ws, size_t ws_size,
                              hipStream_t stream) {
    const float* weights   = (const float*)d_in[0];
    const float* distances = (const float*)d_in[1];
    const float* W1 = (const float*)d_in[2];
    const float* b1 = (const float*)d_in[3];
    const float* W2 = (const float*)d_in[4];
    const float* b2 = (const float*)d_in[5];
    const float* W3 = (const float*)d_in[6];
    const float* b3 = (const float*)d_in[7];
    float* out = (float*)d_out;

    const int rows_total = 4 * 1024;            // B * N
    dim3 grid(rows_total * (NDIM / SEG) / 4);   // 2048 blocks, 4 waves each
    lf_kernel<<<grid, 256, 0, stream>>>(weights, distances, W1, b1, W2, b2, W3, b3, out);
}

// Round 6
// 101.445 us; speedup vs baseline: 1.0379x; 1.0379x over previous
//
#include <hip/hip_runtime.h>

#define HCH 32
#define NDIM 1024
#define SEG 512                  // pixels per wave (half row)
#define PAIRS (SEG / 64)         // 8 iterations of 64 px (2 MFMA tiles)

using half2v   = __attribute__((ext_vector_type(2))) _Float16;
using half8    = __attribute__((ext_vector_type(8))) _Float16;
using floatx16 = __attribute__((ext_vector_type(16))) float;

// One wave per half-row (b,i,seg).
// Stage the wave's whole d/wj stream (512 px each) into private LDS with
// 4x global_load_dwordx4 up front (4 KB in flight/wave -> HBM latency-BW
// covered), then run 8x 64-px pairs entirely from LDS:
//   layer1 packed f16 -> 2x v_mfma_f32_32x32x16_f16 per tile (D[ch][px]),
//   f32 relu+fma dot with W3 per tile, ONE shfl_xor(32) resolves both tiles,
//   softplus f32, one coalesced 256B store (all 64 lanes).
__global__ __launch_bounds__(256, 4)
void lf_kernel(const float* __restrict__ weights,
               const float* __restrict__ distances,
               const float* __restrict__ W1,
               const float* __restrict__ b1,
               const float* __restrict__ W2,
               const float* __restrict__ b2,
               const float* __restrict__ W3,
               const float* __restrict__ b3,
               float* __restrict__ out)
{
    __shared__ float sd[4][SEG];   // per-wave private d chunk (2 KB/wave)
    __shared__ float sw[4][SEG];   // per-wave private wj chunk

    const int lane = threadIdx.x & 63;
    const int wv = threadIdx.x >> 6;
    const int wave_gid = __builtin_amdgcn_readfirstlane(blockIdx.x * 4 + wv);
    const int row_id = wave_gid >> 1;          // (b,i) row
    const int j_begin = (wave_gid & 1) * SEG;  // half within the row
    const int b = row_id >> 10;                // N = 1024

    const int col = lane & 31;                 // pixel-in-tile (B n-index, D col)
    const int half_id = lane >> 5;
    const bool hi = (half_id != 0);
    const int kb = half_id * 8;                // k-block base for A/B frags

    const float* __restrict__ drow = distances + (size_t)row_id * NDIM + j_begin;
    const float* __restrict__ wrow = weights + b * NDIM + j_begin;
    float* __restrict__ orow = out + (size_t)row_id * NDIM + j_begin;

    // ---- Issue the bulk stream loads FIRST (16 B/lane x4 = 4 KB in flight) ----
    const float4 dv0 = *(const float4*)(drow + 4 * lane);
    const float4 dv1 = *(const float4*)(drow + 256 + 4 * lane);
    const float4 wv0 = *(const float4*)(wrow + 4 * lane);
    const float4 wv1 = *(const float4*)(wrow + 256 + 4 * lane);

    // ---- Weight prologue (overlaps the stream loads) ----
    const float wi = weights[row_id];

    // Layer-1 constants as f16 pairs. Pair p<4 -> channels kb+2p,+1 (frag0);
    // p>=4 -> 16+kb+2(p-4)+{0,1} (frag1). base = W1[0,ch]*wi + b1[ch] (f32 fold).
    half2v base2[8], cc2[8], ee2[8];
#pragma unroll
    for (int p = 0; p < 8; ++p) {
        const int chA = (p < 4) ? (kb + 2 * p) : (16 + kb + 2 * (p - 4));
        const int chB = chA + 1;
        base2[p] = half2v{(_Float16)fmaf(W1[chA], wi, b1[chA]),
                          (_Float16)fmaf(W1[chB], wi, b1[chB])};
        cc2[p] = half2v{(_Float16)W1[HCH + chA], (_Float16)W1[HCH + chB]};
        ee2[p] = half2v{(_Float16)W1[2 * HCH + chA], (_Float16)W1[2 * HCH + chB]};
    }

    // A fragments: A[m=c][k=h] = W2[h][c]; c = col, h = kb+j / 16+kb+j.
    half8 a0, a1;
#pragma unroll
    for (int j = 0; j < 8; ++j) {
        a0[j] = (_Float16)W2[(kb + j) * HCH + col];
        a1[j] = (_Float16)W2[(16 + kb + j) * HCH + col];
    }

    // C-init = b2 broadcast along cols; W3 gathered per accumulator register.
    // D row for reg r: (r&3) + 8*(r>>2) + 4*half_id  [measured C/D layout, 32x32]
    floatx16 cinit;
    float w3r[16];
#pragma unroll
    for (int r = 0; r < 16; ++r) {
        const int rc = (r & 3) + 8 * (r >> 2) + 4 * half_id;
        cinit[r] = b2[rc];
        w3r[r]   = W3[rc];
    }
    const float b3v = b3[0];

    // ---- Park the streams in LDS (vmcnt waits happen here) ----
    *(float4*)&sd[wv][4 * lane]       = dv0;
    *(float4*)&sd[wv][256 + 4 * lane] = dv1;
    *(float4*)&sw[wv][4 * lane]       = wv0;
    *(float4*)&sw[wv][256 + 4 * lane] = wv1;
    __syncthreads();

    const half2v zero2 = half2v{(_Float16)0.0f, (_Float16)0.0f};

#pragma unroll
    for (int p = 0; p < PAIRS; ++p) {
        // Stream values from LDS: lanes 0..31 / 32..63 read identical
        // addresses (broadcast, conflict-free).
        const float dA = sd[wv][p * 64 + col];
        const float dB = sd[wv][p * 64 + 32 + col];
        const float wA = sw[wv][p * 64 + col];
        const float wB = sw[wv][p * 64 + 32 + col];

        // ---- Layer 1 (packed f16), two independent tiles ----
        const _Float16 dhA = (_Float16)dA, wjhA = (_Float16)wA;
        const _Float16 dhB = (_Float16)dB, wjhB = (_Float16)wB;
        const half2v d2A = half2v{dhA, dhA}, wj2A = half2v{wjhA, wjhA};
        const half2v d2B = half2v{dhB, dhB}, wj2B = half2v{wjhB, wjhB};

        union Frag { half8 v; half2v h[4]; } f0A, f1A, f0B, f1B;
#pragma unroll
        for (int q = 0; q < 4; ++q) {
            half2v tA0 = __builtin_elementwise_fma(cc2[q], wj2A, base2[q]);
            tA0 = __builtin_elementwise_fma(ee2[q], d2A, tA0);
            f0A.h[q] = __builtin_elementwise_max(tA0, zero2);
            half2v tA1 = __builtin_elementwise_fma(cc2[q + 4], wj2A, base2[q + 4]);
            tA1 = __builtin_elementwise_fma(ee2[q + 4], d2A, tA1);
            f1A.h[q] = __builtin_elementwise_max(tA1, zero2);
            half2v tB0 = __builtin_elementwise_fma(cc2[q], wj2B, base2[q]);
            tB0 = __builtin_elementwise_fma(ee2[q], d2B, tB0);
            f0B.h[q] = __builtin_elementwise_max(tB0, zero2);
            half2v tB1 = __builtin_elementwise_fma(cc2[q + 4], wj2B, base2[q + 4]);
            tB1 = __builtin_elementwise_fma(ee2[q + 4], d2B, tB1);
            f1B.h[q] = __builtin_elementwise_max(tB1, zero2);
        }

        // ---- Layer 2: two independent MFMA chains ----
        floatx16 accA = __builtin_amdgcn_mfma_f32_32x32x16_f16(a0, f0A.v, cinit, 0, 0, 0);
        floatx16 accB = __builtin_amdgcn_mfma_f32_32x32x16_f16(a0, f0B.v, cinit, 0, 0, 0);
        accA = __builtin_amdgcn_mfma_f32_32x32x16_f16(a1, f1A.v, accA, 0, 0, 0);
        accB = __builtin_amdgcn_mfma_f32_32x32x16_f16(a1, f1B.v, accB, 0, 0, 0);

        // ---- Layer 3: relu + W3 dot, two tiles interleaved ----
        float sA0 = 0.0f, sA1 = 0.0f, sB0 = 0.0f, sB1 = 0.0f;
#pragma unroll
        for (int r = 0; r < 16; r += 2) {
            sA0 = fmaf(fmaxf(accA[r + 0], 0.0f), w3r[r + 0], sA0);
            sA1 = fmaf(fmaxf(accA[r + 1], 0.0f), w3r[r + 1], sA1);
            sB0 = fmaf(fmaxf(accB[r + 0], 0.0f), w3r[r + 0], sB0);
            sB1 = fmaf(fmaxf(accB[r + 1], 0.0f), w3r[r + 1], sB1);
        }
        const float sA = sA0 + sA1;
        const float sB = sB0 + sB1;

        // One shuffle resolves both tiles: send the tile the other half needs.
        const float u = hi ? sA : sB;
        const float other = __shfl_xor(u, 32, 64);
        const float loc = hi ? sB : sA;
        const float full = loc + other;  // lane<32: tileA col; lane>=32: tileB col

        // softplus(x) = max(x,0) + log(1 + exp(-|x|)), 64 distinct pixels
        const float x = full + b3v;
        const float sp = fmaxf(x, 0.0f) + __logf(1.0f + __expf(-fabsf(x)));

        orow[p * 64 + lane] = sp;  // coalesced 256B, all 64 lanes

    }
}

extern "C" void kernel_launch(void* const* d_in, const int* in_sizes, int n_in,
                              void* d_out, int out_size, void* d_ws, size_t ws_size,
                              hipStream_t stream) {
    const float* weights   = (const float*)d_in[0];
    const float* distances = (const float*)d_in[1];
    const float* W1 = (const float*)d_in[2];
    const float* b1 = (const float*)d_in[3];
    const float* W2 = (const float*)d_in[4];
    const float* b2 = (const float*)d_in[5];
    const float* W3 = (const float*)d_in[6];
    const float* b3 = (const float*)d_in[7];
    float* out = (float*)d_out;

    const int rows_total = 4 * 1024;            // B * N
    dim3 grid(rows_total * (NDIM / SEG) / 4);   // 2048 blocks, 4 waves each
    lf_kernel<<<grid, 256, 0, stream>>>(weights, distances, W1, b1, W2, b2, W3, b3, out);
}